// Round 4
// baseline (5359.065 us; speedup 1.0000x reference)
//
#include <hip/hip_runtime.h>
#include <math.h>

#define TYPE_VOCAB 30
#define TOPK 50
#define NUM_TYPE 10
#define NB 512
#define NTOT 200000
#define DIN_I 1024
#define DIN_S 300
#define PDIM 256
#define CHUNK 25600
#define NCHUNK 8
#define PRE 2048
#define SCAP 7616        // survivor capacity per row
#define MERGE_CAP 120    // 64 threads * 120 >= SCAP + 50
#define ICAP 28

__device__ __forceinline__ float gelu_exact(float x) {
    return 0.5f * x * (1.0f + erff(x * 0.70710678118654752440f));
}

// (val desc, idx asc) — matches jax.lax.top_k tie-break
__device__ __forceinline__ bool key_gt(float v1, int i1, float v2, int i2) {
    return (v1 > v2) || (v1 == v2 && i1 < i2);
}

// ============================================================================
// Fused ProjectionHead + LayerNorm + L2 normalize, W read DIRECT from L2
// (no W staging, no phase-1 barriers). 256 threads, 32 rows/block.
// Thread (tyy,txx): rows tyy*2+{0,1}, cols j4*64+txx*4+q.
// Requires nrows % 32 == 0 (guaranteed by launch).
// LDS: GsT 8.7 KB only. Target 4 waves/SIMD.
// ============================================================================
__global__ __launch_bounds__(256, 4) void proj_head_kernel(
    const float* __restrict__ X, int nrows, int din,
    const float* __restrict__ W1, const float* __restrict__ B1,
    const float* __restrict__ W2, const float* __restrict__ B2,
    const float* __restrict__ Gm, const float* __restrict__ Bt,
    float* __restrict__ Y)
{
    __shared__ float GsT[64][34];   // [k_local][row] gelu(z) quarter transpose

    const int tid = threadIdx.x;
    const int txx = tid & 15;
    const int tyy = tid >> 4;             // 0..15
    const int r0 = blockIdx.x * 32 + tyy * 2;
    const int r1 = r0 + 1;

    float z0[16], z1[16];
#pragma unroll
    for (int j = 0; j < 16; ++j) { z0[j] = 0.f; z1[j] = 0.f; }

    const float* xp0 = X + (size_t)r0 * din;
    const float* xp1 = X + (size_t)r1 * din;

    // ---- phase 1: z = X @ W1 (W1 direct from L2, X direct, no barriers) ----
    for (int k = 0; k < din; k += 4) {
        float4 a0 = *reinterpret_cast<const float4*>(xp0 + k);
        float4 a1 = *reinterpret_cast<const float4*>(xp1 + k);
        float a0v[4] = {a0.x, a0.y, a0.z, a0.w};
        float a1v[4] = {a1.x, a1.y, a1.z, a1.w};
#pragma unroll
        for (int kk = 0; kk < 4; ++kk) {
            const float* wr = W1 + (size_t)(k + kk) * PDIM + txx * 4;
#pragma unroll
            for (int j4 = 0; j4 < 4; ++j4) {
                float4 w = *reinterpret_cast<const float4*>(wr + j4 * 64);
                float wv[4] = {w.x, w.y, w.z, w.w};
#pragma unroll
                for (int q = 0; q < 4; ++q) {
                    z0[j4 * 4 + q] = fmaf(a0v[kk], wv[q], z0[j4 * 4 + q]);
                    z1[j4 * 4 + q] = fmaf(a1v[kk], wv[q], z1[j4 * 4 + q]);
                }
            }
        }
    }

    // z += b1
#pragma unroll
    for (int j4 = 0; j4 < 4; ++j4) {
        float4 b = *reinterpret_cast<const float4*>(&B1[j4 * 64 + txx * 4]);
        float bv[4] = {b.x, b.y, b.z, b.w};
#pragma unroll
        for (int q = 0; q < 4; ++q) { z0[j4 * 4 + q] += bv[q]; z1[j4 * 4 + q] += bv[q]; }
    }

    // ---- phase 2: h = gelu(z) @ W2, 4 quarters of 64 k; W2 direct from L2 ----
    float h0[16], h1[16];
#pragma unroll
    for (int j = 0; j < 16; ++j) { h0[j] = 0.f; h1[j] = 0.f; }

#pragma unroll 1
    for (int q2 = 0; q2 < 4; ++q2) {
        if (q2 > 0) __syncthreads();
        // this thread's cols with j4 == q2 -> k_local = txx*4+qq
#pragma unroll
        for (int qq = 0; qq < 4; ++qq) {
            GsT[txx * 4 + qq][tyy * 2 + 0] = gelu_exact(z0[q2 * 4 + qq]);
            GsT[txx * 4 + qq][tyy * 2 + 1] = gelu_exact(z1[q2 * 4 + qq]);
        }
        __syncthreads();
#pragma unroll 4
        for (int kk = 0; kk < 64; ++kk) {
            float2 g = *reinterpret_cast<const float2*>(&GsT[kk][tyy * 2]);
            const float* wr = W2 + (size_t)(q2 * 64 + kk) * PDIM + txx * 4;
#pragma unroll
            for (int j4 = 0; j4 < 4; ++j4) {
                float4 w = *reinterpret_cast<const float4*>(wr + j4 * 64);
                float wv[4] = {w.x, w.y, w.z, w.w};
#pragma unroll
                for (int q = 0; q < 4; ++q) {
                    h0[j4 * 4 + q] = fmaf(g.x, wv[q], h0[j4 * 4 + q]);
                    h1[j4 * 4 + q] = fmaf(g.y, wv[q], h1[j4 * 4 + q]);
                }
            }
        }
    }

    // ---- h = h + b2 + z ; LayerNorm ; L2 normalize ; store ----
    float s0 = 0.f, s0q = 0.f, s1 = 0.f, s1q = 0.f;
#pragma unroll
    for (int j4 = 0; j4 < 4; ++j4) {
        float4 b = *reinterpret_cast<const float4*>(&B2[j4 * 64 + txx * 4]);
        float bv[4] = {b.x, b.y, b.z, b.w};
#pragma unroll
        for (int q = 0; q < 4; ++q) {
            float v0 = h0[j4 * 4 + q] + bv[q] + z0[j4 * 4 + q];
            float v1 = h1[j4 * 4 + q] + bv[q] + z1[j4 * 4 + q];
            h0[j4 * 4 + q] = v0; h1[j4 * 4 + q] = v1;
            s0 += v0; s0q += v0 * v0;
            s1 += v1; s1q += v1 * v1;
        }
    }
#pragma unroll
    for (int m = 1; m < 16; m <<= 1) {
        s0 += __shfl_xor(s0, m, 64);  s0q += __shfl_xor(s0q, m, 64);
        s1 += __shfl_xor(s1, m, 64);  s1q += __shfl_xor(s1q, m, 64);
    }
    float mu0 = s0 * (1.f / PDIM), mu1 = s1 * (1.f / PDIM);
    float rs0 = 1.f / sqrtf(s0q * (1.f / PDIM) - mu0 * mu0 + 1e-5f);
    float rs1 = 1.f / sqrtf(s1q * (1.f / PDIM) - mu1 * mu1 + 1e-5f);

    float n0 = 0.f, n1 = 0.f;
#pragma unroll
    for (int j4 = 0; j4 < 4; ++j4) {
        float4 g = *reinterpret_cast<const float4*>(&Gm[j4 * 64 + txx * 4]);
        float4 be = *reinterpret_cast<const float4*>(&Bt[j4 * 64 + txx * 4]);
        float gv[4] = {g.x, g.y, g.z, g.w};
        float bev[4] = {be.x, be.y, be.z, be.w};
#pragma unroll
        for (int q = 0; q < 4; ++q) {
            float u0 = gv[q] * (h0[j4 * 4 + q] - mu0) * rs0 + bev[q];
            float u1 = gv[q] * (h1[j4 * 4 + q] - mu1) * rs1 + bev[q];
            h0[j4 * 4 + q] = u0; h1[j4 * 4 + q] = u1;
            n0 += u0 * u0; n1 += u1 * u1;
        }
    }
#pragma unroll
    for (int m = 1; m < 16; m <<= 1) {
        n0 += __shfl_xor(n0, m, 64);
        n1 += __shfl_xor(n1, m, 64);
    }
    float inv0 = 1.f / fmaxf(sqrtf(n0), 1e-12f);
    float inv1 = 1.f / fmaxf(sqrtf(n1), 1e-12f);

#pragma unroll
    for (int j4 = 0; j4 < 4; ++j4) {
        int c = j4 * 64 + txx * 4;
        *reinterpret_cast<float4*>(&Y[(size_t)r0 * PDIM + c]) =
            make_float4(h0[j4 * 4] * inv0, h0[j4 * 4 + 1] * inv0,
                        h0[j4 * 4 + 2] * inv0, h0[j4 * 4 + 3] * inv0);
        *reinterpret_cast<float4*>(&Y[(size_t)r1 * PDIM + c]) =
            make_float4(h1[j4 * 4] * inv1, h1[j4 * 4 + 1] * inv1,
                        h1[j4 * 4 + 2] * inv1, h1[j4 * 4 + 3] * inv1);
    }
}

// ============================================================================
// sim = A [512,256] @ Bm[chunk]^T.  Tile 128 img-rows x 128 cols, 256 threads,
// 8x8 acc. A direct from L2 (512 KB, shared by all blocks); only B staged
// (16.5 KB LDS). Grid: 4 x ceil(cols/128) = up to 800 blocks per chunk.
// mode 0: dense write to C (prepass). mode 1: threshold filter -> survivors.
// ============================================================================
__global__ __launch_bounds__(256, 3) void sim_gemm_kernel(
    const float* __restrict__ A, const float* __restrict__ Bm,
    int nrows, int colbase0, int gibase, int mode,
    float* __restrict__ C, int ldc,
    const float* __restrict__ stateV, const int* __restrict__ stateI,
    float* __restrict__ survV, int* __restrict__ survI, int* __restrict__ cnt)
{
    __shared__ float Bs[32][132];   // [kk][col], pad 132 (2-way max)

    const int tid = threadIdx.x;
    const int txx = tid & 15;
    const int tyy = tid >> 4;       // 0..15
    const int rowbase = blockIdx.y * 128;
    const int cb = colbase0 + blockIdx.x * 128;

    float acc[8][8];
#pragma unroll
    for (int i = 0; i < 8; ++i)
#pragma unroll
        for (int j = 0; j < 8; ++j) acc[i][j] = 0.f;

    const float* ap = A + (size_t)(rowbase + tyy * 8) * PDIM;

    for (int k0 = 0; k0 < PDIM; k0 += 32) {
        // stage B chunk: 128 cols x 32 k, transposed [k][col]
#pragma unroll
        for (int q = 0; q < 4; ++q) {
            int flat = q * 256 + tid;
            int col = flat & 127;
            int kq = flat >> 7;         // 0..7
            int gcol = cb + col;
            float4 v = make_float4(0.f, 0.f, 0.f, 0.f);
            if (gcol < nrows)
                v = *reinterpret_cast<const float4*>(&Bm[(size_t)gcol * PDIM + k0 + kq * 4]);
            Bs[kq * 4 + 0][col] = v.x;
            Bs[kq * 4 + 1][col] = v.y;
            Bs[kq * 4 + 2][col] = v.z;
            Bs[kq * 4 + 3][col] = v.w;
        }
        __syncthreads();
#pragma unroll
        for (int kq = 0; kq < 8; ++kq) {
            float arr[8][4];
#pragma unroll
            for (int i = 0; i < 8; ++i) {
                float4 a = *reinterpret_cast<const float4*>(ap + (size_t)i * PDIM + k0 + kq * 4);
                arr[i][0] = a.x; arr[i][1] = a.y; arr[i][2] = a.z; arr[i][3] = a.w;
            }
#pragma unroll
            for (int qq = 0; qq < 4; ++qq) {
                float4 b0 = *reinterpret_cast<const float4*>(&Bs[kq * 4 + qq][txx * 4]);
                float4 b1 = *reinterpret_cast<const float4*>(&Bs[kq * 4 + qq][64 + txx * 4]);
                float bv[8] = {b0.x, b0.y, b0.z, b0.w, b1.x, b1.y, b1.z, b1.w};
#pragma unroll
                for (int i = 0; i < 8; ++i) {
                    float a = arr[i][qq];
#pragma unroll
                    for (int j = 0; j < 8; ++j)
                        acc[i][j] = fmaf(a, bv[j], acc[i][j]);
                }
            }
        }
        __syncthreads();
    }

    if (mode == 0) {
#pragma unroll
        for (int i = 0; i < 8; ++i) {
            int ri = rowbase + tyy * 8 + i;
            *reinterpret_cast<float4*>(&C[(size_t)ri * ldc + cb + txx * 4]) =
                make_float4(acc[i][0], acc[i][1], acc[i][2], acc[i][3]);
            *reinterpret_cast<float4*>(&C[(size_t)ri * ldc + cb + 64 + txx * 4]) =
                make_float4(acc[i][4], acc[i][5], acc[i][6], acc[i][7]);
        }
    } else {
#pragma unroll
        for (int i = 0; i < 8; ++i) {
            int ri = rowbase + tyy * 8 + i;
            float tv = stateV[ri * TOPK + TOPK - 1];
            int ti = stateI[ri * TOPK + TOPK - 1];
#pragma unroll
            for (int j = 0; j < 8; ++j) {
                int c = cb + (j >> 2) * 64 + txx * 4 + (j & 3);
                if (c < nrows) {
                    float v = acc[i][j];
                    int gi = gibase + c;
                    if (key_gt(v, gi, tv, ti)) {
                        int pos = atomicAdd(&cnt[ri], 1);
                        if (pos < SCAP) {
                            survV[(size_t)ri * SCAP + pos] = v;
                            survI[(size_t)ri * SCAP + pos] = gi;
                        }
                    }
                }
            }
        }
    }
}

// ============================================================================
// Initial top-50 from the dense prepass matrix (one block per image row).
// Also zeroes survivor counters.
// ============================================================================
__global__ __launch_bounds__(256) void topk_init_kernel(
    const float* __restrict__ C, int ldc, int ncols,
    float* __restrict__ stateV, int* __restrict__ stateI, int* __restrict__ cnt)
{
    __shared__ float lv[256 * ICAP];
    __shared__ int   li[256 * ICAP];
    __shared__ float wrv[4];
    __shared__ int   wri[4];
    __shared__ int   wrt[4];
    __shared__ int   winnerS;
    __shared__ float outV[TOPK];
    __shared__ int   outI[TOPK];

    const int tid = threadIdx.x;
    const int b = blockIdx.x;
    const int off = tid * ICAP;
    int n_l = 0;

    auto ins = [&](float v, int gi) {
        if (n_l == ICAP) {
            if (!key_gt(v, gi, lv[off + ICAP - 1], li[off + ICAP - 1])) return;
            int p = ICAP - 1;
            while (p > 0 && key_gt(v, gi, lv[off + p - 1], li[off + p - 1])) {
                lv[off + p] = lv[off + p - 1];
                li[off + p] = li[off + p - 1];
                --p;
            }
            lv[off + p] = v; li[off + p] = gi;
        } else {
            int p = n_l;
            while (p > 0 && key_gt(v, gi, lv[off + p - 1], li[off + p - 1])) {
                lv[off + p] = lv[off + p - 1];
                li[off + p] = li[off + p - 1];
                --p;
            }
            lv[off + p] = v; li[off + p] = gi;
            ++n_l;
        }
    };

    for (int e = tid; e < ncols; e += 256) ins(C[(size_t)b * ldc + e], e);
    __syncthreads();

    int head = 0;
    for (int r = 0; r < TOPK; ++r) {
        float hv; int hi;
        if (head < n_l) { hv = lv[off + head]; hi = li[off + head]; }
        else { hv = -3.402823466e38f; hi = 0x7fffffff; }
        int ht = tid;
#pragma unroll
        for (int m = 32; m > 0; m >>= 1) {
            float ov = __shfl_xor(hv, m, 64);
            int oi = __shfl_xor(hi, m, 64);
            int ot = __shfl_xor(ht, m, 64);
            if (key_gt(ov, oi, hv, hi)) { hv = ov; hi = oi; ht = ot; }
        }
        if ((tid & 63) == 0) { int w = tid >> 6; wrv[w] = hv; wri[w] = hi; wrt[w] = ht; }
        __syncthreads();
        if (tid == 0) {
            float bv = wrv[0]; int bi = wri[0]; int bt = wrt[0];
#pragma unroll
            for (int w = 1; w < 4; ++w)
                if (key_gt(wrv[w], wri[w], bv, bi)) { bv = wrv[w]; bi = wri[w]; bt = wrt[w]; }
            outV[r] = bv; outI[r] = bi; winnerS = bt;
        }
        __syncthreads();
        if (tid == winnerS) ++head;
    }
    __syncthreads();
    if (tid < TOPK) {
        stateV[b * TOPK + tid] = outV[tid];
        stateI[b * TOPK + tid] = outI[tid];
    }
    if (tid == 0) cnt[b] = 0;
}

// ============================================================================
// Merge survivors into running top-50. One 64-thread wave per row.
// ============================================================================
__global__ __launch_bounds__(64) void surv_merge_kernel(
    const float* __restrict__ survV, const int* __restrict__ survI,
    int* __restrict__ cnt,
    float* __restrict__ stateV, int* __restrict__ stateI)
{
    __shared__ float lv[64 * MERGE_CAP];
    __shared__ int   li[64 * MERGE_CAP];

    const int tid = threadIdx.x;
    const int b = blockIdx.x;
    int n = cnt[b];
    if (n > SCAP) n = SCAP;
    const int off = tid * MERGE_CAP;
    int n_l = 0;

    auto ins = [&](float v, int gi) {
        if (n_l == MERGE_CAP) {
            if (!key_gt(v, gi, lv[off + MERGE_CAP - 1], li[off + MERGE_CAP - 1])) return;
            int p = MERGE_CAP - 1;
            while (p > 0 && key_gt(v, gi, lv[off + p - 1], li[off + p - 1])) {
                lv[off + p] = lv[off + p - 1];
                li[off + p] = li[off + p - 1];
                --p;
            }
            lv[off + p] = v; li[off + p] = gi;
        } else {
            int p = n_l;
            while (p > 0 && key_gt(v, gi, lv[off + p - 1], li[off + p - 1])) {
                lv[off + p] = lv[off + p - 1];
                li[off + p] = li[off + p - 1];
                --p;
            }
            lv[off + p] = v; li[off + p] = gi;
            ++n_l;
        }
    };

    if (tid < TOPK) ins(stateV[b * TOPK + tid], stateI[b * TOPK + tid]);
    for (int e = tid; e < n; e += 64)
        ins(survV[(size_t)b * SCAP + e], survI[(size_t)b * SCAP + e]);

    int head = 0;
    float myV = 0.f; int myI = 0;
    for (int r = 0; r < TOPK; ++r) {
        float hv; int hi;
        if (head < n_l) { hv = lv[off + head]; hi = li[off + head]; }
        else { hv = -3.402823466e38f; hi = 0x7fffffff; }
        int ht = tid;
#pragma unroll
        for (int m = 1; m < 64; m <<= 1) {
            float ov = __shfl_xor(hv, m, 64);
            int oi = __shfl_xor(hi, m, 64);
            int ot = __shfl_xor(ht, m, 64);
            if (key_gt(ov, oi, hv, hi)) { hv = ov; hi = oi; ht = ot; }
        }
        if (tid == ht) ++head;
        if (tid == r) { myV = hv; myI = hi; }
    }
    if (tid < TOPK) {
        stateV[b * TOPK + tid] = myV;
        stateI[b * TOPK + tid] = myI;
    }
    if (tid == 0) cnt[b] = 0;
}

// ============================================================================
// Histogram -> top-10 types -> keep mask -> weighted mean; conf mask.
// ============================================================================
__global__ __launch_bounds__(256) void finalize_kernel(
    const float* __restrict__ stateV, const int* __restrict__ stateI,
    const int* __restrict__ ctype, const float* __restrict__ all_expr,
    float* __restrict__ out)
{
    const int b = blockIdx.x;
    const int tid = threadIdx.x;
    __shared__ int s_idx[TOPK];
    __shared__ int s_type[TOPK];
    __shared__ int s_keep[TOPK];
    __shared__ int s_cnt[TYPE_VOCAB];
    __shared__ unsigned s_keptmask;
    __shared__ float s_wsum;

    if (tid < TYPE_VOCAB) s_cnt[tid] = 0;
    __syncthreads();
    if (tid < TOPK) {
        int gi = stateI[b * TOPK + tid];
        s_idx[tid] = gi;
        int tpe = ctype[gi];
        s_type[tid] = tpe;
        atomicAdd(&s_cnt[tpe], 1);
    }
    __syncthreads();
    if (tid == 0) {
        unsigned kept = 0, used = 0;
        for (int r = 0; r < NUM_TYPE; ++r) {
            int bc = -1, bt = -1;
            for (int tt = 0; tt < TYPE_VOCAB; ++tt) {
                if (used & (1u << tt)) continue;
                if (s_cnt[tt] > bc) { bc = s_cnt[tt]; bt = tt; }
            }
            used |= 1u << bt;
            if (bc > 0) kept |= 1u << bt;
        }
        s_keptmask = kept;
        float sum = 0.f;
        for (int k = 0; k < TOPK; ++k) sum += stateV[b * TOPK + k];
        out[b] = (sum * (1.f / TOPK) > 0.1f) ? 1.0f : 0.0f;
    }
    __syncthreads();
    if (tid < TOPK) s_keep[tid] = (s_keptmask >> s_type[tid]) & 1u;
    __syncthreads();
    if (tid == 0) {
        int w = 0;
        for (int k = 0; k < TOPK; ++k) w += s_keep[k];
        s_wsum = (float)w;
    }
    __syncthreads();
    float wsum = s_wsum;
    for (int d = tid; d < DIN_S; d += 256) {
        float sacc = 0.f;
        for (int k = 0; k < TOPK; ++k)
            if (s_keep[k]) sacc += all_expr[(size_t)s_idx[k] * DIN_S + d];
        out[NB + (size_t)b * DIN_S + d] = sacc / wsum;
    }
}

extern "C" void kernel_launch(void* const* d_in, const int* in_sizes, int n_in,
                              void* d_out, int out_size, void* d_ws, size_t ws_size,
                              hipStream_t stream)
{
    const float* feature       = (const float*)d_in[0];
    const float* all_expr      = (const float*)d_in[1];
    const int*   all_cell_type = (const int*)d_in[2];
    const float* iw1 = (const float*)d_in[3];
    const float* ib1 = (const float*)d_in[4];
    const float* iw2 = (const float*)d_in[5];
    const float* ib2 = (const float*)d_in[6];
    const float* ig  = (const float*)d_in[7];
    const float* ibt = (const float*)d_in[8];
    const float* sw1 = (const float*)d_in[9];
    const float* sb1 = (const float*)d_in[10];
    const float* sw2 = (const float*)d_in[11];
    const float* sb2 = (const float*)d_in[12];
    const float* sg  = (const float*)d_in[13];
    const float* sbt = (const float*)d_in[14];

    float* ws = (float*)d_ws;
    float* img_norm   = ws;                                       // 512*256
    float* expr_chunk = img_norm + (size_t)NB * PDIM;             // 25600*256
    float* sim_pre    = expr_chunk + (size_t)CHUNK * PDIM;        // 512*2048
    float* stateV     = sim_pre + (size_t)NB * PRE;               // 512*50
    int*   stateI     = (int*)(stateV + (size_t)NB * TOPK);       // 512*50
    float* survV      = (float*)(stateI + (size_t)NB * TOPK);     // 512*SCAP
    int*   survI      = (int*)(survV + (size_t)NB * SCAP);        // 512*SCAP
    int*   cnt        = survI + (size_t)NB * SCAP;                // 512

    // projection heads (nrows always a multiple of 32)
    proj_head_kernel<<<NB / 32, 256, 0, stream>>>(
        feature, NB, DIN_I, iw1, ib1, iw2, ib2, ig, ibt, img_norm);
    proj_head_kernel<<<CHUNK / 32, 256, 0, stream>>>(
        all_expr, CHUNK, DIN_S, sw1, sb1, sw2, sb2, sg, sbt, expr_chunk);

    // prepass: dense sim on first PRE cols -> initial top-50 + threshold
    {
        dim3 g(PRE / 128, NB / 128);
        sim_gemm_kernel<<<g, 256, 0, stream>>>(
            img_norm, expr_chunk, PRE, 0, 0, 0, sim_pre, PRE,
            nullptr, nullptr, nullptr, nullptr, nullptr);
        topk_init_kernel<<<NB, 256, 0, stream>>>(sim_pre, PRE, PRE, stateV, stateI, cnt);
    }

    // chunk 0 remainder (cols PRE..CHUNK), filtered
    {
        dim3 g((CHUNK - PRE) / 128, NB / 128);
        sim_gemm_kernel<<<g, 256, 0, stream>>>(
            img_norm, expr_chunk, CHUNK, PRE, 0, 1, nullptr, 0,
            stateV, stateI, survV, survI, cnt);
        surv_merge_kernel<<<NB, 64, 0, stream>>>(survV, survI, cnt, stateV, stateI);
    }

    // chunks 1..7
    for (int c = 1; c < NCHUNK; ++c) {
        int c0 = c * CHUNK;
        int rows = (NTOT - c0 < CHUNK) ? (NTOT - c0) : CHUNK;
        proj_head_kernel<<<rows / 32, 256, 0, stream>>>(
            all_expr + (size_t)c0 * DIN_S, rows, DIN_S,
            sw1, sb1, sw2, sb2, sg, sbt, expr_chunk);
        dim3 g((rows + 127) / 128, NB / 128);
        sim_gemm_kernel<<<g, 256, 0, stream>>>(
            img_norm, expr_chunk, rows, 0, c0, 1, nullptr, 0,
            stateV, stateI, survV, survI, cnt);
        surv_merge_kernel<<<NB, 64, 0, stream>>>(survV, survI, cnt, stateV, stateI);
    }

    finalize_kernel<<<NB, 256, 0, stream>>>(
        stateV, stateI, all_cell_type, all_expr, (float*)d_out);
}

// Round 5
// 3316.430 us; speedup vs baseline: 1.6159x; 1.6159x over previous
//
#include <hip/hip_runtime.h>
#include <math.h>

#define TYPE_VOCAB 30
#define TOPK 50
#define NUM_TYPE 10
#define NB 512
#define NTOT 200000
#define DIN_I 1024
#define DIN_S 300
#define PDIM 256
#define CHUNK 32768
#define PRE 2048
#define SCAP 3072        // survivor capacity per row (E ~140/chunk)
#define MERGE_CAP 49     // 64*49 >= SCAP + 50
#define ICAP 8           // PRE/256

__device__ __forceinline__ float gelu_exact(float x) {
    return 0.5f * x * (1.0f + erff(x * 0.70710678118654752440f));
}

// (val desc, idx asc) — matches jax.lax.top_k tie-break
__device__ __forceinline__ bool key_gt(float v1, int i1, float v2, int i2) {
    return (v1 > v2) || (v1 == v2 && i1 < i2);
}

// ============================================================================
// K1: Z = X @ W1 + b1.   128 rows x 256 cols per block, 256 threads,
// 8x16 acc/thread (0.75 B LDS per FMA -> FMA-bound).
// ============================================================================
__global__ __launch_bounds__(256, 2) void k1_xw1(
    const float* __restrict__ X, int nrows, int din,
    const float* __restrict__ W1, const float* __restrict__ B1,
    float* __restrict__ Z)
{
    __shared__ float Ws[32][PDIM];   // 32 KB [kk][col]
    __shared__ float Xs[32][128];    // 16 KB [kk][row]

    const int tid = threadIdx.x;
    const int txx = tid & 15;
    const int tyy = tid >> 4;        // 0..15
    const int rb = blockIdx.x * 128;

    float acc[8][16];
#pragma unroll
    for (int i = 0; i < 8; ++i)
#pragma unroll
        for (int j = 0; j < 16; ++j) acc[i][j] = 0.f;

    for (int k0 = 0; k0 < din; k0 += 32) {
        const int klen = min(32, din - k0);   // din % 4 == 0 always
        // stage X tile (transposed)
#pragma unroll
        for (int q = 0; q < 4; ++q) {
            int flat = q * 256 + tid;
            int row = flat & 127;
            int kq = flat >> 7;               // 0..7
            int grow = rb + row;
            float4 v = make_float4(0.f, 0.f, 0.f, 0.f);
            if (grow < nrows && kq * 4 < klen)
                v = *reinterpret_cast<const float4*>(&X[(size_t)grow * din + k0 + kq * 4]);
            Xs[kq * 4 + 0][row] = v.x;
            Xs[kq * 4 + 1][row] = v.y;
            Xs[kq * 4 + 2][row] = v.z;
            Xs[kq * 4 + 3][row] = v.w;
        }
        // stage W tile
#pragma unroll
        for (int q = 0; q < 8; ++q) {
            int flat = q * 1024 + tid * 4;
            int kk = flat >> 8;
            int col = flat & 255;
            float4 v = make_float4(0.f, 0.f, 0.f, 0.f);
            if (kk < klen)
                v = *reinterpret_cast<const float4*>(&W1[(size_t)(k0 + kk) * PDIM + col]);
            *reinterpret_cast<float4*>(&Ws[kk][col]) = v;
        }
        __syncthreads();
#pragma unroll 2
        for (int kk = 0; kk < 32; ++kk) {
            float4 x0 = *reinterpret_cast<const float4*>(&Xs[kk][tyy * 8]);
            float4 x1 = *reinterpret_cast<const float4*>(&Xs[kk][tyy * 8 + 4]);
            float xv[8] = {x0.x, x0.y, x0.z, x0.w, x1.x, x1.y, x1.z, x1.w};
            float wv[16];
#pragma unroll
            for (int j4 = 0; j4 < 4; ++j4) {
                float4 w = *reinterpret_cast<const float4*>(&Ws[kk][j4 * 64 + txx * 4]);
                wv[j4 * 4 + 0] = w.x; wv[j4 * 4 + 1] = w.y;
                wv[j4 * 4 + 2] = w.z; wv[j4 * 4 + 3] = w.w;
            }
#pragma unroll
            for (int i = 0; i < 8; ++i)
#pragma unroll
                for (int j = 0; j < 16; ++j)
                    acc[i][j] = fmaf(xv[i], wv[j], acc[i][j]);
        }
        __syncthreads();
    }

    // += b1 ; store Z
#pragma unroll
    for (int j4 = 0; j4 < 4; ++j4) {
        float4 b = *reinterpret_cast<const float4*>(&B1[j4 * 64 + txx * 4]);
        float bv[4] = {b.x, b.y, b.z, b.w};
#pragma unroll
        for (int i = 0; i < 8; ++i)
#pragma unroll
            for (int q = 0; q < 4; ++q) acc[i][j4 * 4 + q] += bv[q];
    }
#pragma unroll
    for (int i = 0; i < 8; ++i) {
        int grow = rb + tyy * 8 + i;
        if (grow < nrows) {
#pragma unroll
            for (int j4 = 0; j4 < 4; ++j4)
                *reinterpret_cast<float4*>(&Z[(size_t)grow * PDIM + j4 * 64 + txx * 4]) =
                    make_float4(acc[i][j4 * 4], acc[i][j4 * 4 + 1],
                                acc[i][j4 * 4 + 2], acc[i][j4 * 4 + 3]);
        }
    }
}

// ============================================================================
// K2: h = gelu(Z) @ W2 + b2 + Z ; LayerNorm ; L2-normalize -> Y.
// Same tiling as K1 (K=256 fixed). gelu applied while staging the A-tile.
// ============================================================================
__global__ __launch_bounds__(256, 2) void k2_gw2(
    const float* __restrict__ Z, int nrows,
    const float* __restrict__ W2, const float* __restrict__ B2,
    const float* __restrict__ Gm, const float* __restrict__ Bt,
    float* __restrict__ Y)
{
    __shared__ float Ws[32][PDIM];
    __shared__ float Gs[32][128];

    const int tid = threadIdx.x;
    const int txx = tid & 15;
    const int tyy = tid >> 4;
    const int rb = blockIdx.x * 128;

    float acc[8][16];
#pragma unroll
    for (int i = 0; i < 8; ++i)
#pragma unroll
        for (int j = 0; j < 16; ++j) acc[i][j] = 0.f;

    for (int k0 = 0; k0 < PDIM; k0 += 32) {
#pragma unroll
        for (int q = 0; q < 4; ++q) {
            int flat = q * 256 + tid;
            int row = flat & 127;
            int kq = flat >> 7;
            int grow = rb + row;
            float4 v = make_float4(0.f, 0.f, 0.f, 0.f);
            if (grow < nrows)
                v = *reinterpret_cast<const float4*>(&Z[(size_t)grow * PDIM + k0 + kq * 4]);
            Gs[kq * 4 + 0][row] = gelu_exact(v.x);
            Gs[kq * 4 + 1][row] = gelu_exact(v.y);
            Gs[kq * 4 + 2][row] = gelu_exact(v.z);
            Gs[kq * 4 + 3][row] = gelu_exact(v.w);
        }
#pragma unroll
        for (int q = 0; q < 8; ++q) {
            int flat = q * 1024 + tid * 4;
            int kk = flat >> 8;
            int col = flat & 255;
            *reinterpret_cast<float4*>(&Ws[kk][col]) =
                *reinterpret_cast<const float4*>(&W2[(size_t)(k0 + kk) * PDIM + col]);
        }
        __syncthreads();
#pragma unroll 2
        for (int kk = 0; kk < 32; ++kk) {
            float4 x0 = *reinterpret_cast<const float4*>(&Gs[kk][tyy * 8]);
            float4 x1 = *reinterpret_cast<const float4*>(&Gs[kk][tyy * 8 + 4]);
            float xv[8] = {x0.x, x0.y, x0.z, x0.w, x1.x, x1.y, x1.z, x1.w};
            float wv[16];
#pragma unroll
            for (int j4 = 0; j4 < 4; ++j4) {
                float4 w = *reinterpret_cast<const float4*>(&Ws[kk][j4 * 64 + txx * 4]);
                wv[j4 * 4 + 0] = w.x; wv[j4 * 4 + 1] = w.y;
                wv[j4 * 4 + 2] = w.z; wv[j4 * 4 + 3] = w.w;
            }
#pragma unroll
            for (int i = 0; i < 8; ++i)
#pragma unroll
                for (int j = 0; j < 16; ++j)
                    acc[i][j] = fmaf(xv[i], wv[j], acc[i][j]);
        }
        __syncthreads();
    }

    // epilogue: h = acc + b2 + z ; LN ; L2 norm ; store
    float s[8], s2[8];
#pragma unroll
    for (int i = 0; i < 8; ++i) { s[i] = 0.f; s2[i] = 0.f; }

#pragma unroll
    for (int j4 = 0; j4 < 4; ++j4) {
        float4 b = *reinterpret_cast<const float4*>(&B2[j4 * 64 + txx * 4]);
        float bv[4] = {b.x, b.y, b.z, b.w};
#pragma unroll
        for (int i = 0; i < 8; ++i) {
            int grow = rb + tyy * 8 + i;
            float4 z4 = make_float4(0.f, 0.f, 0.f, 0.f);
            if (grow < nrows)
                z4 = *reinterpret_cast<const float4*>(&Z[(size_t)grow * PDIM + j4 * 64 + txx * 4]);
            float zv[4] = {z4.x, z4.y, z4.z, z4.w};
#pragma unroll
            for (int q = 0; q < 4; ++q) {
                float v = acc[i][j4 * 4 + q] + bv[q] + zv[q];
                acc[i][j4 * 4 + q] = v;
                s[i] += v; s2[i] += v * v;
            }
        }
    }
    // reduce across the 16 txx lanes of each row (consecutive lanes in wave)
#pragma unroll
    for (int m = 1; m < 16; m <<= 1)
#pragma unroll
        for (int i = 0; i < 8; ++i) {
            s[i] += __shfl_xor(s[i], m, 64);
            s2[i] += __shfl_xor(s2[i], m, 64);
        }
    float mu[8], rs[8];
#pragma unroll
    for (int i = 0; i < 8; ++i) {
        mu[i] = s[i] * (1.f / PDIM);
        rs[i] = 1.f / sqrtf(s2[i] * (1.f / PDIM) - mu[i] * mu[i] + 1e-5f);
    }
    float nn[8];
#pragma unroll
    for (int i = 0; i < 8; ++i) nn[i] = 0.f;
#pragma unroll
    for (int j4 = 0; j4 < 4; ++j4) {
        float4 g = *reinterpret_cast<const float4*>(&Gm[j4 * 64 + txx * 4]);
        float4 be = *reinterpret_cast<const float4*>(&Bt[j4 * 64 + txx * 4]);
        float gv[4] = {g.x, g.y, g.z, g.w};
        float bev[4] = {be.x, be.y, be.z, be.w};
#pragma unroll
        for (int i = 0; i < 8; ++i)
#pragma unroll
            for (int q = 0; q < 4; ++q) {
                float u = gv[q] * (acc[i][j4 * 4 + q] - mu[i]) * rs[i] + bev[q];
                acc[i][j4 * 4 + q] = u;
                nn[i] += u * u;
            }
    }
#pragma unroll
    for (int m = 1; m < 16; m <<= 1)
#pragma unroll
        for (int i = 0; i < 8; ++i) nn[i] += __shfl_xor(nn[i], m, 64);
#pragma unroll
    for (int i = 0; i < 8; ++i) {
        float inv = 1.f / fmaxf(sqrtf(nn[i]), 1e-12f);
        int grow = rb + tyy * 8 + i;
        if (grow < nrows) {
#pragma unroll
            for (int j4 = 0; j4 < 4; ++j4)
                *reinterpret_cast<float4*>(&Y[(size_t)grow * PDIM + j4 * 64 + txx * 4]) =
                    make_float4(acc[i][j4 * 4] * inv, acc[i][j4 * 4 + 1] * inv,
                                acc[i][j4 * 4 + 2] * inv, acc[i][j4 * 4 + 3] * inv);
        }
    }
}

// ============================================================================
// sim = A [512,256] @ Bm[chunk]^T.  128 img-rows x 256 cols, 256 threads,
// 8x16 acc (0.75 B/FMA). mode 0: dense C. mode 1: threshold -> survivors.
// ============================================================================
__global__ __launch_bounds__(256, 2) void sim_gemm_kernel(
    const float* __restrict__ A, const float* __restrict__ Bm,
    int nrows, int colbase0, int gibase, int mode,
    float* __restrict__ C, int ldc,
    const float* __restrict__ stateV, const int* __restrict__ stateI,
    float* __restrict__ survV, int* __restrict__ survI, int* __restrict__ cnt)
{
    __shared__ float Bs[32][PDIM];   // 32 KB [kk][col]
    __shared__ float As[32][128];    // 16 KB [kk][row]

    const int tid = threadIdx.x;
    const int txx = tid & 15;
    const int tyy = tid >> 4;
    const int rowbase = blockIdx.y * 128;
    const int cb = colbase0 + blockIdx.x * 256;

    float acc[8][16];
#pragma unroll
    for (int i = 0; i < 8; ++i)
#pragma unroll
        for (int j = 0; j < 16; ++j) acc[i][j] = 0.f;

    for (int k0 = 0; k0 < PDIM; k0 += 32) {
#pragma unroll
        for (int q = 0; q < 4; ++q) {
            int flat = q * 256 + tid;
            int row = flat & 127;
            int kq = flat >> 7;
            float4 v = *reinterpret_cast<const float4*>(
                &A[(size_t)(rowbase + row) * PDIM + k0 + kq * 4]);
            As[kq * 4 + 0][row] = v.x;
            As[kq * 4 + 1][row] = v.y;
            As[kq * 4 + 2][row] = v.z;
            As[kq * 4 + 3][row] = v.w;
        }
#pragma unroll
        for (int q = 0; q < 8; ++q) {
            int flat = q * 256 + tid;
            int col = flat & 255;
            int kq = flat >> 8;
            int gcol = cb + col;
            float4 v = make_float4(0.f, 0.f, 0.f, 0.f);
            if (gcol < nrows)
                v = *reinterpret_cast<const float4*>(&Bm[(size_t)gcol * PDIM + k0 + kq * 4]);
            Bs[kq * 4 + 0][col] = v.x;
            Bs[kq * 4 + 1][col] = v.y;
            Bs[kq * 4 + 2][col] = v.z;
            Bs[kq * 4 + 3][col] = v.w;
        }
        __syncthreads();
#pragma unroll 2
        for (int kk = 0; kk < 32; ++kk) {
            float4 a0 = *reinterpret_cast<const float4*>(&As[kk][tyy * 8]);
            float4 a1 = *reinterpret_cast<const float4*>(&As[kk][tyy * 8 + 4]);
            float av[8] = {a0.x, a0.y, a0.z, a0.w, a1.x, a1.y, a1.z, a1.w};
            float bw[16];
#pragma unroll
            for (int j4 = 0; j4 < 4; ++j4) {
                float4 b = *reinterpret_cast<const float4*>(&Bs[kk][j4 * 64 + txx * 4]);
                bw[j4 * 4 + 0] = b.x; bw[j4 * 4 + 1] = b.y;
                bw[j4 * 4 + 2] = b.z; bw[j4 * 4 + 3] = b.w;
            }
#pragma unroll
            for (int i = 0; i < 8; ++i)
#pragma unroll
                for (int j = 0; j < 16; ++j)
                    acc[i][j] = fmaf(av[i], bw[j], acc[i][j]);
        }
        __syncthreads();
    }

    if (mode == 0) {
#pragma unroll
        for (int i = 0; i < 8; ++i) {
            int ri = rowbase + tyy * 8 + i;
#pragma unroll
            for (int j4 = 0; j4 < 4; ++j4)
                *reinterpret_cast<float4*>(&C[(size_t)ri * ldc + cb + j4 * 64 + txx * 4]) =
                    make_float4(acc[i][j4 * 4], acc[i][j4 * 4 + 1],
                                acc[i][j4 * 4 + 2], acc[i][j4 * 4 + 3]);
        }
    } else {
#pragma unroll
        for (int i = 0; i < 8; ++i) {
            int ri = rowbase + tyy * 8 + i;
            float tv = stateV[ri * TOPK + TOPK - 1];
            int ti = stateI[ri * TOPK + TOPK - 1];
#pragma unroll
            for (int j = 0; j < 16; ++j) {
                int c = cb + (j >> 2) * 64 + txx * 4 + (j & 3);
                if (c < nrows) {
                    float v = acc[i][j];
                    int gi = gibase + c;
                    if (key_gt(v, gi, tv, ti)) {
                        int pos = atomicAdd(&cnt[ri], 1);
                        if (pos < SCAP) {
                            survV[(size_t)ri * SCAP + pos] = v;
                            survI[(size_t)ri * SCAP + pos] = gi;
                        }
                    }
                }
            }
        }
    }
}

// ============================================================================
// Initial top-50 from dense prepass (one block per image row); zero counters.
// ============================================================================
__global__ __launch_bounds__(256) void topk_init_kernel(
    const float* __restrict__ C, int ldc, int ncols,
    float* __restrict__ stateV, int* __restrict__ stateI, int* __restrict__ cnt)
{
    __shared__ float lv[256 * ICAP];
    __shared__ int   li[256 * ICAP];
    __shared__ float wrv[4];
    __shared__ int   wri[4];
    __shared__ int   wrt[4];
    __shared__ int   winnerS;
    __shared__ float outV[TOPK];
    __shared__ int   outI[TOPK];

    const int tid = threadIdx.x;
    const int b = blockIdx.x;
    const int off = tid * ICAP;
    int n_l = 0;

    auto ins = [&](float v, int gi) {
        int p = n_l;
        while (p > 0 && key_gt(v, gi, lv[off + p - 1], li[off + p - 1])) {
            lv[off + p] = lv[off + p - 1];
            li[off + p] = li[off + p - 1];
            --p;
        }
        lv[off + p] = v; li[off + p] = gi;
        ++n_l;
    };

    for (int e = tid; e < ncols; e += 256) ins(C[(size_t)b * ldc + e], e);
    __syncthreads();

    int head = 0;
    for (int r = 0; r < TOPK; ++r) {
        float hv; int hi;
        if (head < n_l) { hv = lv[off + head]; hi = li[off + head]; }
        else { hv = -3.402823466e38f; hi = 0x7fffffff; }
        int ht = tid;
#pragma unroll
        for (int m = 32; m > 0; m >>= 1) {
            float ov = __shfl_xor(hv, m, 64);
            int oi = __shfl_xor(hi, m, 64);
            int ot = __shfl_xor(ht, m, 64);
            if (key_gt(ov, oi, hv, hi)) { hv = ov; hi = oi; ht = ot; }
        }
        if ((tid & 63) == 0) { int w = tid >> 6; wrv[w] = hv; wri[w] = hi; wrt[w] = ht; }
        __syncthreads();
        if (tid == 0) {
            float bv = wrv[0]; int bi = wri[0]; int bt = wrt[0];
#pragma unroll
            for (int w = 1; w < 4; ++w)
                if (key_gt(wrv[w], wri[w], bv, bi)) { bv = wrv[w]; bi = wri[w]; bt = wrt[w]; }
            outV[r] = bv; outI[r] = bi; winnerS = bt;
        }
        __syncthreads();
        if (tid == winnerS) ++head;
    }
    __syncthreads();
    if (tid < TOPK) {
        stateV[b * TOPK + tid] = outV[tid];
        stateI[b * TOPK + tid] = outI[tid];
    }
    if (tid == 0) cnt[b] = 0;
}

// ============================================================================
// Merge survivors into running top-50. One 64-thread wave per row.
// ============================================================================
__global__ __launch_bounds__(64) void surv_merge_kernel(
    const float* __restrict__ survV, const int* __restrict__ survI,
    int* __restrict__ cnt,
    float* __restrict__ stateV, int* __restrict__ stateI)
{
    __shared__ float lv[64 * MERGE_CAP];
    __shared__ int   li[64 * MERGE_CAP];

    const int tid = threadIdx.x;
    const int b = blockIdx.x;
    int n = cnt[b];
    if (n > SCAP) n = SCAP;
    const int off = tid * MERGE_CAP;
    int n_l = 0;

    auto ins = [&](float v, int gi) {
        int p = n_l;
        while (p > 0 && key_gt(v, gi, lv[off + p - 1], li[off + p - 1])) {
            lv[off + p] = lv[off + p - 1];
            li[off + p] = li[off + p - 1];
            --p;
        }
        lv[off + p] = v; li[off + p] = gi;
        ++n_l;
    };

    if (tid < TOPK) ins(stateV[b * TOPK + tid], stateI[b * TOPK + tid]);
    for (int e = tid; e < n; e += 64)
        ins(survV[(size_t)b * SCAP + e], survI[(size_t)b * SCAP + e]);

    int head = 0;
    float myV = 0.f; int myI = 0;
    for (int r = 0; r < TOPK; ++r) {
        float hv; int hi;
        if (head < n_l) { hv = lv[off + head]; hi = li[off + head]; }
        else { hv = -3.402823466e38f; hi = 0x7fffffff; }
        int ht = tid;
#pragma unroll
        for (int m = 1; m < 64; m <<= 1) {
            float ov = __shfl_xor(hv, m, 64);
            int oi = __shfl_xor(hi, m, 64);
            int ot = __shfl_xor(ht, m, 64);
            if (key_gt(ov, oi, hv, hi)) { hv = ov; hi = oi; ht = ot; }
        }
        if (tid == ht) ++head;
        if (tid == r) { myV = hv; myI = hi; }
    }
    if (tid < TOPK) {
        stateV[b * TOPK + tid] = myV;
        stateI[b * TOPK + tid] = myI;
    }
    if (tid == 0) cnt[b] = 0;
}

// ============================================================================
// Histogram -> top-10 types -> keep mask -> weighted mean; conf mask.
// ============================================================================
__global__ __launch_bounds__(256) void finalize_kernel(
    const float* __restrict__ stateV, const int* __restrict__ stateI,
    const int* __restrict__ ctype, const float* __restrict__ all_expr,
    float* __restrict__ out)
{
    const int b = blockIdx.x;
    const int tid = threadIdx.x;
    __shared__ int s_idx[TOPK];
    __shared__ int s_type[TOPK];
    __shared__ int s_keep[TOPK];
    __shared__ int s_cnt[TYPE_VOCAB];
    __shared__ unsigned s_keptmask;
    __shared__ float s_wsum;

    if (tid < TYPE_VOCAB) s_cnt[tid] = 0;
    __syncthreads();
    if (tid < TOPK) {
        int gi = stateI[b * TOPK + tid];
        s_idx[tid] = gi;
        int tpe = ctype[gi];
        s_type[tid] = tpe;
        atomicAdd(&s_cnt[tpe], 1);
    }
    __syncthreads();
    if (tid == 0) {
        unsigned kept = 0, used = 0;
        for (int r = 0; r < NUM_TYPE; ++r) {
            int bc = -1, bt = -1;
            for (int tt = 0; tt < TYPE_VOCAB; ++tt) {
                if (used & (1u << tt)) continue;
                if (s_cnt[tt] > bc) { bc = s_cnt[tt]; bt = tt; }
            }
            used |= 1u << bt;
            if (bc > 0) kept |= 1u << bt;
        }
        s_keptmask = kept;
        float sum = 0.f;
        for (int k = 0; k < TOPK; ++k) sum += stateV[b * TOPK + k];
        out[b] = (sum * (1.f / TOPK) > 0.1f) ? 1.0f : 0.0f;
    }
    __syncthreads();
    if (tid < TOPK) s_keep[tid] = (s_keptmask >> s_type[tid]) & 1u;
    __syncthreads();
    if (tid == 0) {
        int w = 0;
        for (int k = 0; k < TOPK; ++k) w += s_keep[k];
        s_wsum = (float)w;
    }
    __syncthreads();
    float wsum = s_wsum;
    for (int d = tid; d < DIN_S; d += 256) {
        float sacc = 0.f;
        for (int k = 0; k < TOPK; ++k)
            if (s_keep[k]) sacc += all_expr[(size_t)s_idx[k] * DIN_S + d];
        out[NB + (size_t)b * DIN_S + d] = sacc / wsum;
    }
}

extern "C" void kernel_launch(void* const* d_in, const int* in_sizes, int n_in,
                              void* d_out, int out_size, void* d_ws, size_t ws_size,
                              hipStream_t stream)
{
    const float* feature       = (const float*)d_in[0];
    const float* all_expr      = (const float*)d_in[1];
    const int*   all_cell_type = (const int*)d_in[2];
    const float* iw1 = (const float*)d_in[3];
    const float* ib1 = (const float*)d_in[4];
    const float* iw2 = (const float*)d_in[5];
    const float* ib2 = (const float*)d_in[6];
    const float* ig  = (const float*)d_in[7];
    const float* ibt = (const float*)d_in[8];
    const float* sw1 = (const float*)d_in[9];
    const float* sb1 = (const float*)d_in[10];
    const float* sw2 = (const float*)d_in[11];
    const float* sb2 = (const float*)d_in[12];
    const float* sg  = (const float*)d_in[13];
    const float* sbt = (const float*)d_in[14];

    // workspace layout (67.8 MB total; Z aliases sim_pre+surv — Z is dead
    // before sim mode0/mode1 write into the union region):
    float* ws = (float*)d_ws;
    float* img_norm   = ws;                                       // 512*256
    float* expr_chunk = img_norm + (size_t)NB * PDIM;             // 32768*256
    float* stateV     = expr_chunk + (size_t)CHUNK * PDIM;        // 512*50
    int*   stateI     = (int*)(stateV + (size_t)NB * TOPK);      // 512*50
    int*   cnt        = stateI + (size_t)NB * TOPK;               // 512
    float* uni        = (float*)(cnt + NB);                       // union region
    float* Z          = uni;                                      // 32768*256
    float* sim_pre    = uni;                                      // 512*2048
    float* survV      = uni + (size_t)NB * PRE;                   // 512*SCAP
    int*   survI      = (int*)(survV + (size_t)NB * SCAP);        // 512*SCAP

    // image projection (512 rows = 4 blocks)
    k1_xw1<<<NB / 128, 256, 0, stream>>>(feature, NB, DIN_I, iw1, ib1, Z);
    k2_gw2<<<NB / 128, 256, 0, stream>>>(Z, NB, iw2, ib2, ig, ibt, img_norm);

    int chunk_id = 0;
    for (int c0 = 0; c0 < NTOT; c0 += CHUNK, ++chunk_id) {
        int rows = (NTOT - c0 < CHUNK) ? (NTOT - c0) : CHUNK;

        k1_xw1<<<(rows + 127) / 128, 256, 0, stream>>>(
            all_expr + (size_t)c0 * DIN_S, rows, DIN_S, sw1, sb1, Z);
        k2_gw2<<<(rows + 127) / 128, 256, 0, stream>>>(
            Z, rows, sw2, sb2, sg, sbt, expr_chunk);

        if (chunk_id == 0) {
            // prepass: dense sim on first PRE cols -> initial top-50
            dim3 g0(PRE / 256, NB / 128);
            sim_gemm_kernel<<<g0, 256, 0, stream>>>(
                img_norm, expr_chunk, PRE, 0, 0, 0, sim_pre, PRE,
                nullptr, nullptr, nullptr, nullptr, nullptr);
            topk_init_kernel<<<NB, 256, 0, stream>>>(
                sim_pre, PRE, PRE, stateV, stateI, cnt);
            // remainder of chunk 0, filtered
            dim3 g1((CHUNK - PRE) / 256, NB / 128);
            sim_gemm_kernel<<<g1, 256, 0, stream>>>(
                img_norm, expr_chunk, rows, PRE, 0, 1, nullptr, 0,
                stateV, stateI, survV, survI, cnt);
            surv_merge_kernel<<<NB, 64, 0, stream>>>(survV, survI, cnt, stateV, stateI);
        } else {
            dim3 g((rows + 255) / 256, NB / 128);
            sim_gemm_kernel<<<g, 256, 0, stream>>>(
                img_norm, expr_chunk, rows, 0, c0, 1, nullptr, 0,
                stateV, stateI, survV, survI, cnt);
            surv_merge_kernel<<<NB, 64, 0, stream>>>(survV, survI, cnt, stateV, stateI);
        }
    }

    finalize_kernel<<<NB, 256, 0, stream>>>(
        stateV, stateI, all_cell_type, all_expr, (float*)d_out);
}

// Round 7
// 2700.061 us; speedup vs baseline: 1.9848x; 1.2283x over previous
//
#include <hip/hip_runtime.h>
#include <math.h>

#define TYPE_VOCAB 30
#define TOPK 50
#define NUM_TYPE 10
#define NB 512
#define NTOT 200000
#define DIN_I 1024
#define DIN_S 300
#define PDIM 256
#define CHUNK 32768
#define PRE 2048
#define SCAP 3072        // survivor capacity per row (E ~140/chunk)
#define MERGE_CAP 49     // 64*49 >= SCAP + 50
#define ICAP 8           // PRE/256

__device__ __forceinline__ float gelu_exact(float x) {
    return 0.5f * x * (1.0f + erff(x * 0.70710678118654752440f));
}

// (val desc, idx asc) — matches jax.lax.top_k tie-break
__device__ __forceinline__ bool key_gt(float v1, int i1, float v2, int i2) {
    return (v1 > v2) || (v1 == v2 && i1 < i2);
}

// ============================================================================
// K1: Z = X @ W1 + b1.  Tile 128 rows x 128 cols (col half via blockIdx.y),
// 256 threads, acc 8x8 = 64 VGPR (MUST stay <=64 so acc is register-resident;
// 128-reg acc compiled to AGPR-parking = 5x VALU inflation, R5 post-mortem).
// Grid per 32768-chunk: 256x2 = 512 blocks (>=2/CU, avoids dispatch imbalance).
// K-tail (din=300 -> 12) handled in a separate unmasked post-loop.
// ============================================================================
__global__ __launch_bounds__(256) void k1_xw1(
    const float* __restrict__ X, int nrows, int din,
    const float* __restrict__ W1, const float* __restrict__ B1,
    float* __restrict__ Z)
{
    __shared__ float Xs[32][128];   // 16 KB [kk][row]
    __shared__ float Ws[32][128];   // 16 KB [kk][col]

    const int tid = threadIdx.x;
    const int txx = tid & 15;
    const int tyy = tid >> 4;            // 0..15
    const int rb = blockIdx.x * 128;
    const int cb = blockIdx.y * 128;

    float acc[8][8];
#pragma unroll
    for (int i = 0; i < 8; ++i)
#pragma unroll
        for (int j = 0; j < 8; ++j) acc[i][j] = 0.f;

    int k0 = 0;
    for (; k0 + 32 <= din; k0 += 32) {
        // stage X tile transposed: 128 rows x 32 k (4 float4 / thread)
#pragma unroll
        for (int q = 0; q < 4; ++q) {
            int flat = q * 256 + tid;
            int row = flat & 127;
            int kq = flat >> 7;          // 0..7
            int grow = rb + row;
            float4 v = make_float4(0.f, 0.f, 0.f, 0.f);
            if (grow < nrows)
                v = *reinterpret_cast<const float4*>(&X[(size_t)grow * din + k0 + kq * 4]);
            Xs[kq * 4 + 0][row] = v.x;
            Xs[kq * 4 + 1][row] = v.y;
            Xs[kq * 4 + 2][row] = v.z;
            Xs[kq * 4 + 3][row] = v.w;
        }
        // stage W tile: 32 k x 128 cols (this block's half), 4 float4 / thread
#pragma unroll
        for (int q = 0; q < 4; ++q) {
            int flat = q * 256 + tid;
            int col4 = flat & 31;
            int kk = flat >> 5;          // 0..31
            *reinterpret_cast<float4*>(&Ws[kk][col4 * 4]) =
                *reinterpret_cast<const float4*>(&W1[(size_t)(k0 + kk) * PDIM + cb + col4 * 4]);
        }
        __syncthreads();
#pragma unroll 4
        for (int kk = 0; kk < 32; ++kk) {
            float4 x0 = *reinterpret_cast<const float4*>(&Xs[kk][tyy * 8]);
            float4 x1 = *reinterpret_cast<const float4*>(&Xs[kk][tyy * 8 + 4]);
            float xv[8] = {x0.x, x0.y, x0.z, x0.w, x1.x, x1.y, x1.z, x1.w};
            float4 w0 = *reinterpret_cast<const float4*>(&Ws[kk][txx * 4]);
            float4 w1 = *reinterpret_cast<const float4*>(&Ws[kk][64 + txx * 4]);
            float wv[8] = {w0.x, w0.y, w0.z, w0.w, w1.x, w1.y, w1.z, w1.w};
#pragma unroll
            for (int i = 0; i < 8; ++i)
#pragma unroll
                for (int j = 0; j < 8; ++j)
                    acc[i][j] = fmaf(xv[i], wv[j], acc[i][j]);
        }
        __syncthreads();
    }

    // K tail (din=300: rem=12; din=1024: skipped)
    if (k0 < din) {
        int rem = din - k0;
        for (int e = tid; e < rem * 128; e += 256) {
            int row = e & 127;
            int kk = e >> 7;
            int grow = rb + row;
            Xs[kk][row] = (grow < nrows) ? X[(size_t)grow * din + k0 + kk] : 0.f;
        }
        for (int e = tid; e < rem * 128; e += 256) {
            int col = e & 127;
            int kk = e >> 7;
            Ws[kk][col] = W1[(size_t)(k0 + kk) * PDIM + cb + col];
        }
        __syncthreads();
        for (int kk = 0; kk < rem; ++kk) {
            float4 x0 = *reinterpret_cast<const float4*>(&Xs[kk][tyy * 8]);
            float4 x1 = *reinterpret_cast<const float4*>(&Xs[kk][tyy * 8 + 4]);
            float xv[8] = {x0.x, x0.y, x0.z, x0.w, x1.x, x1.y, x1.z, x1.w};
            float4 w0 = *reinterpret_cast<const float4*>(&Ws[kk][txx * 4]);
            float4 w1 = *reinterpret_cast<const float4*>(&Ws[kk][64 + txx * 4]);
            float wv[8] = {w0.x, w0.y, w0.z, w0.w, w1.x, w1.y, w1.z, w1.w};
#pragma unroll
            for (int i = 0; i < 8; ++i)
#pragma unroll
                for (int j = 0; j < 8; ++j)
                    acc[i][j] = fmaf(xv[i], wv[j], acc[i][j]);
        }
    }

    // += b1 ; store Z (this block's 128-col half)
    float4 bq0 = *reinterpret_cast<const float4*>(&B1[cb + txx * 4]);
    float4 bq1 = *reinterpret_cast<const float4*>(&B1[cb + 64 + txx * 4]);
    float bv[8] = {bq0.x, bq0.y, bq0.z, bq0.w, bq1.x, bq1.y, bq1.z, bq1.w};
#pragma unroll
    for (int i = 0; i < 8; ++i) {
        int grow = rb + tyy * 8 + i;
        if (grow < nrows) {
            *reinterpret_cast<float4*>(&Z[(size_t)grow * PDIM + cb + txx * 4]) =
                make_float4(acc[i][0] + bv[0], acc[i][1] + bv[1],
                            acc[i][2] + bv[2], acc[i][3] + bv[3]);
            *reinterpret_cast<float4*>(&Z[(size_t)grow * PDIM + cb + 64 + txx * 4]) =
                make_float4(acc[i][4] + bv[4], acc[i][5] + bv[5],
                            acc[i][6] + bv[6], acc[i][7] + bv[7]);
        }
    }
}

// ============================================================================
// K2: h = gelu(Z) @ W2 + b2 + Z ; LayerNorm ; L2-normalize -> Y.
// Tile 64 rows x 256 cols (full row needed for the LN reduce), 256 threads,
// acc 4x16 = 64 VGPR. Grid per chunk: rows/64 = 512 blocks.
// Requires nrows % 64 == 0 (32768, 3392, 512 all qualify) -> NO row masks.
// ============================================================================
__global__ __launch_bounds__(256) void k2_gw2(
    const float* __restrict__ Z, int nrows,
    const float* __restrict__ W2, const float* __restrict__ B2,
    const float* __restrict__ Gm, const float* __restrict__ Bt,
    float* __restrict__ Y)
{
    __shared__ float Gs[32][64];     // 8 KB  [kk][row]
    __shared__ float Ws[32][PDIM];   // 32 KB [kk][col]

    const int tid = threadIdx.x;
    const int txx = tid & 15;
    const int tyy = tid >> 4;        // 0..15
    const int rb = blockIdx.x * 64;

    float acc[4][16];
#pragma unroll
    for (int i = 0; i < 4; ++i)
#pragma unroll
        for (int j = 0; j < 16; ++j) acc[i][j] = 0.f;

    for (int k0 = 0; k0 < PDIM; k0 += 32) {
        // stage gelu(Z) tile transposed: 64 rows x 32 k (2 float4 / thread)
#pragma unroll
        for (int q = 0; q < 2; ++q) {
            int flat = q * 256 + tid;
            int row = flat & 63;
            int kq = flat >> 6;          // 0..7
            float4 v = *reinterpret_cast<const float4*>(
                &Z[(size_t)(rb + row) * PDIM + k0 + kq * 4]);
            Gs[kq * 4 + 0][row] = gelu_exact(v.x);
            Gs[kq * 4 + 1][row] = gelu_exact(v.y);
            Gs[kq * 4 + 2][row] = gelu_exact(v.z);
            Gs[kq * 4 + 3][row] = gelu_exact(v.w);
        }
        // stage W2 tile: 32 k x 256 cols (8 float4 / thread)
#pragma unroll
        for (int q = 0; q < 8; ++q) {
            int flat = q * 256 + tid;
            int col4 = flat & 63;
            int kk = flat >> 6;
            *reinterpret_cast<float4*>(&Ws[kk][col4 * 4]) =
                *reinterpret_cast<const float4*>(&W2[(size_t)(k0 + kk) * PDIM + col4 * 4]);
        }
        __syncthreads();
#pragma unroll 4
        for (int kk = 0; kk < 32; ++kk) {
            float4 g4 = *reinterpret_cast<const float4*>(&Gs[kk][tyy * 4]);
            float gv[4] = {g4.x, g4.y, g4.z, g4.w};
            float wv[16];
#pragma unroll
            for (int j4 = 0; j4 < 4; ++j4) {
                float4 w = *reinterpret_cast<const float4*>(&Ws[kk][j4 * 64 + txx * 4]);
                wv[j4 * 4 + 0] = w.x; wv[j4 * 4 + 1] = w.y;
                wv[j4 * 4 + 2] = w.z; wv[j4 * 4 + 3] = w.w;
            }
#pragma unroll
            for (int i = 0; i < 4; ++i)
#pragma unroll
                for (int j = 0; j < 16; ++j)
                    acc[i][j] = fmaf(gv[i], wv[j], acc[i][j]);
        }
        __syncthreads();
    }

    // epilogue: h = acc + b2 + z ; LN ; L2 norm ; store
    float s[4] = {0.f, 0.f, 0.f, 0.f}, s2[4] = {0.f, 0.f, 0.f, 0.f};
#pragma unroll
    for (int j4 = 0; j4 < 4; ++j4) {
        float4 b = *reinterpret_cast<const float4*>(&B2[j4 * 64 + txx * 4]);
        float bq[4] = {b.x, b.y, b.z, b.w};
#pragma unroll
        for (int i = 0; i < 4; ++i) {
            int grow = rb + tyy * 4 + i;
            float4 z4 = *reinterpret_cast<const float4*>(
                &Z[(size_t)grow * PDIM + j4 * 64 + txx * 4]);
            float zv[4] = {z4.x, z4.y, z4.z, z4.w};
#pragma unroll
            for (int q = 0; q < 4; ++q) {
                float v = acc[i][j4 * 4 + q] + bq[q] + zv[q];
                acc[i][j4 * 4 + q] = v;
                s[i] += v; s2[i] += v * v;
            }
        }
    }
#pragma unroll
    for (int m = 1; m < 16; m <<= 1)
#pragma unroll
        for (int i = 0; i < 4; ++i) {
            s[i] += __shfl_xor(s[i], m, 64);
            s2[i] += __shfl_xor(s2[i], m, 64);
        }
    float mu[4], rs[4];
#pragma unroll
    for (int i = 0; i < 4; ++i) {
        mu[i] = s[i] * (1.f / PDIM);
        rs[i] = 1.f / sqrtf(s2[i] * (1.f / PDIM) - mu[i] * mu[i] + 1e-5f);
    }
    float nn[4] = {0.f, 0.f, 0.f, 0.f};
#pragma unroll
    for (int j4 = 0; j4 < 4; ++j4) {
        float4 g = *reinterpret_cast<const float4*>(&Gm[j4 * 64 + txx * 4]);
        float4 be = *reinterpret_cast<const float4*>(&Bt[j4 * 64 + txx * 4]);
        float gq[4] = {g.x, g.y, g.z, g.w};
        float beq[4] = {be.x, be.y, be.z, be.w};
#pragma unroll
        for (int i = 0; i < 4; ++i)
#pragma unroll
            for (int q = 0; q < 4; ++q) {
                float u = gq[q] * (acc[i][j4 * 4 + q] - mu[i]) * rs[i] + beq[q];
                acc[i][j4 * 4 + q] = u;
                nn[i] += u * u;
            }
    }
#pragma unroll
    for (int m = 1; m < 16; m <<= 1)
#pragma unroll
        for (int i = 0; i < 4; ++i) nn[i] += __shfl_xor(nn[i], m, 64);
#pragma unroll
    for (int i = 0; i < 4; ++i) {
        float inv = 1.f / fmaxf(sqrtf(nn[i]), 1e-12f);
        int grow = rb + tyy * 4 + i;
#pragma unroll
        for (int j4 = 0; j4 < 4; ++j4)
            *reinterpret_cast<float4*>(&Y[(size_t)grow * PDIM + j4 * 64 + txx * 4]) =
                make_float4(acc[i][j4 * 4] * inv, acc[i][j4 * 4 + 1] * inv,
                            acc[i][j4 * 4 + 2] * inv, acc[i][j4 * 4 + 3] * inv);
    }
}

// ============================================================================
// sim = A [512,256] @ Bm[chunk]^T.  128 img-rows x 256 cols, 256 threads,
// 8x16 acc. mode 0: dense C. mode 1: threshold -> survivors.
// (UNCHANGED from R5 — measured fast; do not perturb.)
// ============================================================================
__global__ __launch_bounds__(256, 2) void sim_gemm_kernel(
    const float* __restrict__ A, const float* __restrict__ Bm,
    int nrows, int colbase0, int gibase, int mode,
    float* __restrict__ C, int ldc,
    const float* __restrict__ stateV, const int* __restrict__ stateI,
    float* __restrict__ survV, int* __restrict__ survI, int* __restrict__ cnt)
{
    __shared__ float Bs[32][PDIM];   // 32 KB [kk][col]
    __shared__ float As[32][128];    // 16 KB [kk][row]

    const int tid = threadIdx.x;
    const int txx = tid & 15;
    const int tyy = tid >> 4;
    const int rowbase = blockIdx.y * 128;
    const int cb = colbase0 + blockIdx.x * 256;

    float acc[8][16];
#pragma unroll
    for (int i = 0; i < 8; ++i)
#pragma unroll
        for (int j = 0; j < 16; ++j) acc[i][j] = 0.f;

    for (int k0 = 0; k0 < PDIM; k0 += 32) {
#pragma unroll
        for (int q = 0; q < 4; ++q) {
            int flat = q * 256 + tid;
            int row = flat & 127;
            int kq = flat >> 7;
            float4 v = *reinterpret_cast<const float4*>(
                &A[(size_t)(rowbase + row) * PDIM + k0 + kq * 4]);
            As[kq * 4 + 0][row] = v.x;
            As[kq * 4 + 1][row] = v.y;
            As[kq * 4 + 2][row] = v.z;
            As[kq * 4 + 3][row] = v.w;
        }
#pragma unroll
        for (int q = 0; q < 8; ++q) {
            int flat = q * 256 + tid;
            int col = flat & 255;
            int kq = flat >> 8;
            int gcol = cb + col;
            float4 v = make_float4(0.f, 0.f, 0.f, 0.f);
            if (gcol < nrows)
                v = *reinterpret_cast<const float4*>(&Bm[(size_t)gcol * PDIM + k0 + kq * 4]);
            Bs[kq * 4 + 0][col] = v.x;
            Bs[kq * 4 + 1][col] = v.y;
            Bs[kq * 4 + 2][col] = v.z;
            Bs[kq * 4 + 3][col] = v.w;
        }
        __syncthreads();
#pragma unroll 2
        for (int kk = 0; kk < 32; ++kk) {
            float4 a0 = *reinterpret_cast<const float4*>(&As[kk][tyy * 8]);
            float4 a1 = *reinterpret_cast<const float4*>(&As[kk][tyy * 8 + 4]);
            float av[8] = {a0.x, a0.y, a0.z, a0.w, a1.x, a1.y, a1.z, a1.w};
            float bw[16];
#pragma unroll
            for (int j4 = 0; j4 < 4; ++j4) {
                float4 b = *reinterpret_cast<const float4*>(&Bs[kk][j4 * 64 + txx * 4]);
                bw[j4 * 4 + 0] = b.x; bw[j4 * 4 + 1] = b.y;
                bw[j4 * 4 + 2] = b.z; bw[j4 * 4 + 3] = b.w;
            }
#pragma unroll
            for (int i = 0; i < 8; ++i)
#pragma unroll
                for (int j = 0; j < 16; ++j)
                    acc[i][j] = fmaf(av[i], bw[j], acc[i][j]);
        }
        __syncthreads();
    }

    if (mode == 0) {
#pragma unroll
        for (int i = 0; i < 8; ++i) {
            int ri = rowbase + tyy * 8 + i;
#pragma unroll
            for (int j4 = 0; j4 < 4; ++j4)
                *reinterpret_cast<float4*>(&C[(size_t)ri * ldc + cb + j4 * 64 + txx * 4]) =
                    make_float4(acc[i][j4 * 4], acc[i][j4 * 4 + 1],
                                acc[i][j4 * 4 + 2], acc[i][j4 * 4 + 3]);
        }
    } else {
#pragma unroll
        for (int i = 0; i < 8; ++i) {
            int ri = rowbase + tyy * 8 + i;
            float tv = stateV[ri * TOPK + TOPK - 1];
            int ti = stateI[ri * TOPK + TOPK - 1];
#pragma unroll
            for (int j = 0; j < 16; ++j) {
                int c = cb + (j >> 2) * 64 + txx * 4 + (j & 3);
                if (c < nrows) {
                    float v = acc[i][j];
                    int gi = gibase + c;
                    if (key_gt(v, gi, tv, ti)) {
                        int pos = atomicAdd(&cnt[ri], 1);
                        if (pos < SCAP) {
                            survV[(size_t)ri * SCAP + pos] = v;
                            survI[(size_t)ri * SCAP + pos] = gi;
                        }
                    }
                }
            }
        }
    }
}

// ============================================================================
// Initial top-50 from dense prepass (one block per image row); zero counters.
// ============================================================================
__global__ __launch_bounds__(256) void topk_init_kernel(
    const float* __restrict__ C, int ldc, int ncols,
    float* __restrict__ stateV, int* __restrict__ stateI, int* __restrict__ cnt)
{
    __shared__ float lv[256 * ICAP];
    __shared__ int   li[256 * ICAP];
    __shared__ float wrv[4];
    __shared__ int   wri[4];
    __shared__ int   wrt[4];
    __shared__ int   winnerS;
    __shared__ float outV[TOPK];
    __shared__ int   outI[TOPK];

    const int tid = threadIdx.x;
    const int b = blockIdx.x;
    const int off = tid * ICAP;
    int n_l = 0;

    auto ins = [&](float v, int gi) {
        int p = n_l;
        while (p > 0 && key_gt(v, gi, lv[off + p - 1], li[off + p - 1])) {
            lv[off + p] = lv[off + p - 1];
            li[off + p] = li[off + p - 1];
            --p;
        }
        lv[off + p] = v; li[off + p] = gi;
        ++n_l;
    };

    for (int e = tid; e < ncols; e += 256) ins(C[(size_t)b * ldc + e], e);
    __syncthreads();

    int head = 0;
    for (int r = 0; r < TOPK; ++r) {
        float hv; int hi;
        if (head < n_l) { hv = lv[off + head]; hi = li[off + head]; }
        else { hv = -3.402823466e38f; hi = 0x7fffffff; }
        int ht = tid;
#pragma unroll
        for (int m = 32; m > 0; m >>= 1) {
            float ov = __shfl_xor(hv, m, 64);
            int oi = __shfl_xor(hi, m, 64);
            int ot = __shfl_xor(ht, m, 64);
            if (key_gt(ov, oi, hv, hi)) { hv = ov; hi = oi; ht = ot; }
        }
        if ((tid & 63) == 0) { int w = tid >> 6; wrv[w] = hv; wri[w] = hi; wrt[w] = ht; }
        __syncthreads();
        if (tid == 0) {
            float bv = wrv[0]; int bi = wri[0]; int bt = wrt[0];
#pragma unroll
            for (int w = 1; w < 4; ++w)
                if (key_gt(wrv[w], wri[w], bv, bi)) { bv = wrv[w]; bi = wri[w]; bt = wrt[w]; }
            outV[r] = bv; outI[r] = bi; winnerS = bt;
        }
        __syncthreads();
        if (tid == winnerS) ++head;
    }
    __syncthreads();
    if (tid < TOPK) {
        stateV[b * TOPK + tid] = outV[tid];
        stateI[b * TOPK + tid] = outI[tid];
    }
    if (tid == 0) cnt[b] = 0;
}

// ============================================================================
// Merge survivors into running top-50. One 64-thread wave per row.
// ============================================================================
__global__ __launch_bounds__(64) void surv_merge_kernel(
    const float* __restrict__ survV, const int* __restrict__ survI,
    int* __restrict__ cnt,
    float* __restrict__ stateV, int* __restrict__ stateI)
{
    __shared__ float lv[64 * MERGE_CAP];
    __shared__ int   li[64 * MERGE_CAP];

    const int tid = threadIdx.x;
    const int b = blockIdx.x;
    int n = cnt[b];
    if (n > SCAP) n = SCAP;
    const int off = tid * MERGE_CAP;
    int n_l = 0;

    auto ins = [&](float v, int gi) {
        int p = n_l;
        while (p > 0 && key_gt(v, gi, lv[off + p - 1], li[off + p - 1])) {
            lv[off + p] = lv[off + p - 1];
            li[off + p] = li[off + p - 1];
            --p;
        }
        lv[off + p] = v; li[off + p] = gi;
        ++n_l;
    };

    if (tid < TOPK) ins(stateV[b * TOPK + tid], stateI[b * TOPK + tid]);
    for (int e = tid; e < n; e += 64)
        ins(survV[(size_t)b * SCAP + e], survI[(size_t)b * SCAP + e]);

    int head = 0;
    float myV = 0.f; int myI = 0;
    for (int r = 0; r < TOPK; ++r) {
        float hv; int hi;
        if (head < n_l) { hv = lv[off + head]; hi = li[off + head]; }
        else { hv = -3.402823466e38f; hi = 0x7fffffff; }
        int ht = tid;
#pragma unroll
        for (int m = 1; m < 64; m <<= 1) {
            float ov = __shfl_xor(hv, m, 64);
            int oi = __shfl_xor(hi, m, 64);
            int ot = __shfl_xor(ht, m, 64);
            if (key_gt(ov, oi, hv, hi)) { hv = ov; hi = oi; ht = ot; }
        }
        if (tid == ht) ++head;
        if (tid == r) { myV = hv; myI = hi; }
    }
    if (tid < TOPK) {
        stateV[b * TOPK + tid] = myV;
        stateI[b * TOPK + tid] = myI;
    }
    if (tid == 0) cnt[b] = 0;
}

// ============================================================================
// Histogram -> top-10 types -> keep mask -> weighted mean; conf mask.
// ============================================================================
__global__ __launch_bounds__(256) void finalize_kernel(
    const float* __restrict__ stateV, const int* __restrict__ stateI,
    const int* __restrict__ ctype, const float* __restrict__ all_expr,
    float* __restrict__ out)
{
    const int b = blockIdx.x;
    const int tid = threadIdx.x;
    __shared__ int s_idx[TOPK];
    __shared__ int s_type[TOPK];
    __shared__ int s_keep[TOPK];
    __shared__ int s_cnt[TYPE_VOCAB];
    __shared__ unsigned s_keptmask;
    __shared__ float s_wsum;

    if (tid < TYPE_VOCAB) s_cnt[tid] = 0;
    __syncthreads();
    if (tid < TOPK) {
        int gi = stateI[b * TOPK + tid];
        s_idx[tid] = gi;
        int tpe = ctype[gi];
        s_type[tid] = tpe;
        atomicAdd(&s_cnt[tpe], 1);
    }
    __syncthreads();
    if (tid == 0) {
        unsigned kept = 0, used = 0;
        for (int r = 0; r < NUM_TYPE; ++r) {
            int bc = -1, bt = -1;
            for (int tt = 0; tt < TYPE_VOCAB; ++tt) {
                if (used & (1u << tt)) continue;
                if (s_cnt[tt] > bc) { bc = s_cnt[tt]; bt = tt; }
            }
            used |= 1u << bt;
            if (bc > 0) kept |= 1u << bt;
        }
        s_keptmask = kept;
        float sum = 0.f;
        for (int k = 0; k < TOPK; ++k) sum += stateV[b * TOPK + k];
        out[b] = (sum * (1.f / TOPK) > 0.1f) ? 1.0f : 0.0f;
    }
    __syncthreads();
    if (tid < TOPK) s_keep[tid] = (s_keptmask >> s_type[tid]) & 1u;
    __syncthreads();
    if (tid == 0) {
        int w = 0;
        for (int k = 0; k < TOPK; ++k) w += s_keep[k];
        s_wsum = (float)w;
    }
    __syncthreads();
    float wsum = s_wsum;
    for (int d = tid; d < DIN_S; d += 256) {
        float sacc = 0.f;
        for (int k = 0; k < TOPK; ++k)
            if (s_keep[k]) sacc += all_expr[(size_t)s_idx[k] * DIN_S + d];
        out[NB + (size_t)b * DIN_S + d] = sacc / wsum;
    }
}

extern "C" void kernel_launch(void* const* d_in, const int* in_sizes, int n_in,
                              void* d_out, int out_size, void* d_ws, size_t ws_size,
                              hipStream_t stream)
{
    const float* feature       = (const float*)d_in[0];
    const float* all_expr      = (const float*)d_in[1];
    const int*   all_cell_type = (const int*)d_in[2];
    const float* iw1 = (const float*)d_in[3];
    const float* ib1 = (const float*)d_in[4];
    const float* iw2 = (const float*)d_in[5];
    const float* ib2 = (const float*)d_in[6];
    const float* ig  = (const float*)d_in[7];
    const float* ibt = (const float*)d_in[8];
    const float* sw1 = (const float*)d_in[9];
    const float* sb1 = (const float*)d_in[10];
    const float* sw2 = (const float*)d_in[11];
    const float* sb2 = (const float*)d_in[12];
    const float* sg  = (const float*)d_in[13];
    const float* sbt = (const float*)d_in[14];

    // workspace layout (~68 MB; Z aliases sim_pre+surv — Z dead before they
    // are written, surv dead before next chunk's k1 writes Z):
    float* ws = (float*)d_ws;
    float* img_norm   = ws;                                       // 512*256
    float* expr_chunk = img_norm + (size_t)NB * PDIM;             // 32768*256
    float* stateV     = expr_chunk + (size_t)CHUNK * PDIM;        // 512*50
    int*   stateI     = (int*)(stateV + (size_t)NB * TOPK);       // 512*50
    int*   cnt        = stateI + (size_t)NB * TOPK;               // 512
    float* uni        = (float*)(cnt + NB);                       // union region
    float* Z          = uni;                                      // 32768*256
    float* sim_pre    = uni;                                      // 512*2048
    float* survV      = uni + (size_t)NB * PRE;                   // 512*SCAP
    int*   survI      = (int*)(survV + (size_t)NB * SCAP);        // 512*SCAP

    // image projection (512 rows): k1 grid (4,2), k2 grid 8
    {
        dim3 gi1(NB / 128, 2);
        k1_xw1<<<gi1, 256, 0, stream>>>(feature, NB, DIN_I, iw1, ib1, Z);
        k2_gw2<<<NB / 64, 256, 0, stream>>>(Z, NB, iw2, ib2, ig, ibt, img_norm);
    }

    int chunk_id = 0;
    for (int c0 = 0; c0 < NTOT; c0 += CHUNK, ++chunk_id) {
        int rows = (NTOT - c0 < CHUNK) ? (NTOT - c0) : CHUNK;   // 32768 or 3392

        dim3 g1((rows + 127) / 128, 2);
        k1_xw1<<<g1, 256, 0, stream>>>(
            all_expr + (size_t)c0 * DIN_S, rows, DIN_S, sw1, sb1, Z);
        k2_gw2<<<rows / 64, 256, 0, stream>>>(
            Z, rows, sw2, sb2, sg, sbt, expr_chunk);

        if (chunk_id == 0) {
            dim3 g0(PRE / 256, NB / 128);
            sim_gemm_kernel<<<g0, 256, 0, stream>>>(
                img_norm, expr_chunk, PRE, 0, 0, 0, sim_pre, PRE,
                nullptr, nullptr, nullptr, nullptr, nullptr);
            topk_init_kernel<<<NB, 256, 0, stream>>>(
                sim_pre, PRE, PRE, stateV, stateI, cnt);
            dim3 gf((CHUNK - PRE) / 256, NB / 128);
            sim_gemm_kernel<<<gf, 256, 0, stream>>>(
                img_norm, expr_chunk, rows, PRE, 0, 1, nullptr, 0,
                stateV, stateI, survV, survI, cnt);
            surv_merge_kernel<<<NB, 64, 0, stream>>>(survV, survI, cnt, stateV, stateI);
        } else {
            dim3 g((rows + 255) / 256, NB / 128);
            sim_gemm_kernel<<<g, 256, 0, stream>>>(
                img_norm, expr_chunk, rows, 0, c0, 1, nullptr, 0,
                stateV, stateI, survV, survI, cnt);
            surv_merge_kernel<<<NB, 64, 0, stream>>>(survV, survI, cnt, stateV, stateI);
        }
    }

    finalize_kernel<<<NB, 256, 0, stream>>>(
        stateV, stateI, all_cell_type, all_expr, (float*)d_out);
}